// Round 3
// baseline (328.751 us; speedup 1.0000x reference)
//
#include <hip/hip_runtime.h>
#include <hip/hip_bf16.h>
#include <math.h>

#define BATCH 64
#define TLEN 512
#define DIM 768
#define NLAB 50

typedef __attribute__((ext_vector_type(8))) short short8;   // 8 bf16 (4 VGPRs)
typedef __attribute__((ext_vector_type(4))) float f32x4;    // MFMA acc

__device__ __forceinline__ unsigned short f2bf(float f) {
    unsigned int u = __float_as_uint(f);
    return (unsigned short)((u + 0x7FFFu + ((u >> 16) & 1u)) >> 16);
}

// ---------------------------------------------------------------------------
// prep: W fp32 [768 x 50] -> Bt bf16 [64 cols][768 k] (transposed, zero-pad)
// also zeroes out[0] (crf accumulates the loss atomically now).
// ---------------------------------------------------------------------------
__global__ __launch_bounds__(256) void wprep_kernel(const float* __restrict__ W,
                                                    unsigned short* __restrict__ Bt,
                                                    float* __restrict__ out0) {
    int idx = blockIdx.x * 256 + threadIdx.x;
    if (idx == 0) out0[0] = 0.f;
    if (idx < 64 * DIM) {
        int c = idx / DIM;
        int k = idx - c * DIM;
        float v = (c < NLAB) ? W[k * NLAB + c] : 0.f;
        Bt[idx] = f2bf(v);
    }
}

// ---------------------------------------------------------------------------
// GEMM v2 (unchanged from R2): 512 thr / 8 waves, tile 128x64, dbuf LDS.
// ---------------------------------------------------------------------------
#define AST 36
#define BSTC 40

__global__ __launch_bounds__(512)
void gemm_kernel(
    const float* __restrict__ A,              // [32768 x 768] fp32
    const unsigned short* __restrict__ Bt,    // [64 x 768] bf16 (W^T, padded)
    const float* __restrict__ bias,
    float* __restrict__ out)                  // [32768 x 50]
{
    __shared__ float As[2][128 * AST];
    __shared__ short Bs[2][64 * BSTC];

    const int tid = threadIdx.x;
    const int wave = tid >> 6;
    const int lane = tid & 63;
    const int m = lane & 15;
    const int q = lane >> 4;
    const int row0 = blockIdx.x * 128;

    const int r0s = tid >> 2;            // 0..127 (row)
    const int c0s = (tid & 3) * 8;       // k offset {0,8,16,24}
    const int bcol = tid >> 3;           // 0..63
    const int bkk = (tid & 7) * 4;       // 4 shorts per thread

    f32x4 acc0 = {0.f,0.f,0.f,0.f}, acc1 = {0.f,0.f,0.f,0.f};
    f32x4 acc2 = {0.f,0.f,0.f,0.f}, acc3 = {0.f,0.f,0.f,0.f};

    {
        *(float4*)&As[0][r0s * AST + c0s]     = *(const float4*)(A + (size_t)(row0 + r0s) * DIM + c0s);
        *(float4*)&As[0][r0s * AST + c0s + 4] = *(const float4*)(A + (size_t)(row0 + r0s) * DIM + c0s + 4);
        *(short4*)&Bs[0][bcol * BSTC + bkk]   = *(const short4*)(Bt + (size_t)bcol * DIM + bkk);
    }
    __syncthreads();

    int buf = 0;
    for (int ch = 0; ch < DIM / 32; ++ch) {
        const int k0n = (ch + 1) * 32;
        const bool havenext = (ch < DIM / 32 - 1);
        float4 pa0, pa1;
        short4 pb;
        if (havenext) {
            pa0 = *(const float4*)(A + (size_t)(row0 + r0s) * DIM + k0n + c0s);
            pa1 = *(const float4*)(A + (size_t)(row0 + r0s) * DIM + k0n + c0s + 4);
            pb  = *(const short4*)(Bt + (size_t)bcol * DIM + k0n + bkk);
        }

        const short8 bq0 = *(const short8*)&Bs[buf][( 0 + m) * BSTC + q * 8];
        const short8 bq1 = *(const short8*)&Bs[buf][(16 + m) * BSTC + q * 8];
        const short8 bq2 = *(const short8*)&Bs[buf][(32 + m) * BSTC + q * 8];
        const short8 bq3 = *(const short8*)&Bs[buf][(48 + m) * BSTC + q * 8];

        {
            const int rr = wave * 16 + m;
            const float4 xa = *(const float4*)&As[buf][rr * AST + q * 8];
            const float4 xb = *(const float4*)&As[buf][rr * AST + q * 8 + 4];
            short8 af;
            af[0] = (short)f2bf(xa.x); af[1] = (short)f2bf(xa.y);
            af[2] = (short)f2bf(xa.z); af[3] = (short)f2bf(xa.w);
            af[4] = (short)f2bf(xb.x); af[5] = (short)f2bf(xb.y);
            af[6] = (short)f2bf(xb.z); af[7] = (short)f2bf(xb.w);
            acc0 = __builtin_amdgcn_mfma_f32_16x16x32_bf16(af, bq0, acc0, 0, 0, 0);
            acc1 = __builtin_amdgcn_mfma_f32_16x16x32_bf16(af, bq1, acc1, 0, 0, 0);
            acc2 = __builtin_amdgcn_mfma_f32_16x16x32_bf16(af, bq2, acc2, 0, 0, 0);
            acc3 = __builtin_amdgcn_mfma_f32_16x16x32_bf16(af, bq3, acc3, 0, 0, 0);
        }

        if (havenext) {
            const int nb = buf ^ 1;
            *(float4*)&As[nb][r0s * AST + c0s]     = pa0;
            *(float4*)&As[nb][r0s * AST + c0s + 4] = pa1;
            *(short4*)&Bs[nb][bcol * BSTC + bkk]   = pb;
        }
        __syncthreads();
        buf ^= 1;
    }

    const int rb = row0 + wave * 16 + q * 4;
#pragma unroll
    for (int nt = 0; nt < 4; ++nt) {
        const f32x4 av = (nt == 0) ? acc0 : (nt == 1) ? acc1 : (nt == 2) ? acc2 : acc3;
        const int col = nt * 16 + m;
        if (col < NLAB) {
            const float bv = bias[col];
#pragma unroll
            for (int r = 0; r < 4; ++r)
                out[(size_t)(rb + r) * NLAB + col] = av[r] + bv;
        }
    }
}

// ---------------------------------------------------------------------------
// CRF v10: hazard-free broadcast batch.
// v9 measured 668 cyc/step; issue floor is ~250. Theory: v_readlane (VALU->
// SGPR) followed closely by the consuming fma costs ~4-8 wait-states each
// (~400 cyc/step). v10 issues ALL 50 readlanes first (mutually independent,
// all depend only on prev-step ue), fences with sched_barrier(0), then runs
// the 50 fmas -- every SGPR is >=50 instructions old at consumption.
// Loss kernel fused in via one atomicAdd per block (wprep zeroes out[0]).
// ---------------------------------------------------------------------------
__device__ __forceinline__ float wave_sum(float v) {
#pragma unroll
    for (int off = 32; off > 0; off >>= 1) v += __shfl_xor(v, off, 64);
    return v;
}

#define ET_INIT(v, base)                            \
    v.x = __expf(trans[(base + 0) * NLAB + j]);     \
    v.y = __expf(trans[(base + 1) * NLAB + j]);     \
    v.z = __expf(trans[(base + 2) * NLAB + j]);     \
    v.w = __expf(trans[(base + 3) * NLAB + j]);

// broadcast lane i of the raw e-vector (ue) to all lanes
#define RLF(i) __uint_as_float(__builtin_amdgcn_readlane(__float_as_uint(ue), (i)))

__global__ __launch_bounds__(64) __attribute__((amdgpu_waves_per_eu(1, 1)))
void crf_kernel(
    const float* __restrict__ logits,
    const int* __restrict__ labels,
    const void* __restrict__ maskp,
    const float* __restrict__ startT,
    const float* __restrict__ endT,
    const float* __restrict__ trans,
    float* __restrict__ out0) {
    const int b = blockIdx.x;
    const int lane = threadIdx.x;

    // --- mask length (contiguous valid prefix) ---
    const int probe = ((const int*)maskp)[0];
    int len = 0;
    if (probe == 1) {
        const int* mk = (const int*)maskp + b * TLEN;
#pragma unroll
        for (int it = 0; it < 8; ++it)
            len += (int)__popcll(__ballot(mk[lane + it * 64] != 0));
    } else if (probe == 0x01010101) {
        const unsigned char* mk = (const unsigned char*)maskp + b * TLEN;
#pragma unroll
        for (int it = 0; it < 8; ++it)
            len += (int)__popcll(__ballot(mk[lane + it * 64] != 0));
    } else if (probe == 0x3F803F80) {
        const unsigned short* mk = (const unsigned short*)maskp + b * TLEN;
#pragma unroll
        for (int it = 0; it < 8; ++it)
            len += (int)__popcll(__ballot(mk[lane + it * 64] != 0));
    } else {
        const float* mk = (const float*)maskp + b * TLEN;
#pragma unroll
        for (int it = 0; it < 8; ++it)
            len += (int)__popcll(__ballot(mk[lane + it * 64] != 0.f));
    }

    const int j = lane;
    const int jc = (j < NLAB) ? j : (NLAB - 1);

    // et = exp(trans[:, j]) in 13 named float4 registers
    float4 et0  = {0.f,0.f,0.f,0.f}, et1  = {0.f,0.f,0.f,0.f};
    float4 et2  = {0.f,0.f,0.f,0.f}, et3  = {0.f,0.f,0.f,0.f};
    float4 et4  = {0.f,0.f,0.f,0.f}, et5  = {0.f,0.f,0.f,0.f};
    float4 et6  = {0.f,0.f,0.f,0.f}, et7  = {0.f,0.f,0.f,0.f};
    float4 et8  = {0.f,0.f,0.f,0.f}, et9  = {0.f,0.f,0.f,0.f};
    float4 et10 = {0.f,0.f,0.f,0.f}, et11 = {0.f,0.f,0.f,0.f};
    float4 et12 = {0.f,0.f,0.f,0.f};
    if (j < NLAB) {
        ET_INIT(et0,  0)  ET_INIT(et1,  4)  ET_INIT(et2,  8)
        ET_INIT(et3,  12) ET_INIT(et4,  16) ET_INIT(et5,  20)
        ET_INIT(et6,  24) ET_INIT(et7,  28) ET_INIT(et8,  32)
        ET_INIT(et9,  36) ET_INIT(et10, 40) ET_INIT(et11, 44)
        et12.x = __expf(trans[48 * NLAB + j]);
        et12.y = __expf(trans[49 * NLAB + j]);
    }

    const float* em = logits + (size_t)b * TLEN * NLAB;

    float a0v = (j < NLAB) ? (startT[j] + em[j]) : 0.f;
    const float Abc = __shfl(a0v, 0, 64);
    // ue = raw (un-normalized) e-vector value of this lane; lane 0 == 1.0
    float ue = (j < NLAB) ? __expf(a0v - Abc) : 0.f;
    float A = Abc;

    // 4-deep emission pipeline: named scalars, rotated by assignment.
    float q0 = em[1 * NLAB + jc];
    float q1 = em[2 * NLAB + jc];
    float q2 = em[3 * NLAB + jc];
    float q3 = em[4 * NLAB + jc];
    float pcur = __expf(q0);
    q0 = q1; q1 = q2; q2 = q3; q3 = em[5 * NLAB + jc];

    for (int t = 1; t < len; ++t) {
        int tf = t + 5; tf = (tf < len) ? tf : (len - 1);
        const float newem = em[tf * NLAB + jc];      // issued, used 4 iters later
        const float pnext = __expf(q0);              // off-chain

        // ---- broadcast batch: 50 independent readlanes, no consumer between
        const float r0  = RLF(0);  const float r1  = RLF(1);
        const float r2  = RLF(2);  const float r3  = RLF(3);
        const float r4  = RLF(4);  const float r5  = RLF(5);
        const float r6  = RLF(6);  const float r7  = RLF(7);
        const float r8  = RLF(8);  const float r9  = RLF(9);
        const float r10 = RLF(10); const float r11 = RLF(11);
        const float r12 = RLF(12); const float r13 = RLF(13);
        const float r14 = RLF(14); const float r15 = RLF(15);
        const float r16 = RLF(16); const float r17 = RLF(17);
        const float r18 = RLF(18); const float r19 = RLF(19);
        const float r20 = RLF(20); const float r21 = RLF(21);
        const float r22 = RLF(22); const float r23 = RLF(23);
        const float r24 = RLF(24); const float r25 = RLF(25);
        const float r26 = RLF(26); const float r27 = RLF(27);
        const float r28 = RLF(28); const float r29 = RLF(29);
        const float r30 = RLF(30); const float r31 = RLF(31);
        const float r32 = RLF(32); const float r33 = RLF(33);
        const float r34 = RLF(34); const float r35 = RLF(35);
        const float r36 = RLF(36); const float r37 = RLF(37);
        const float r38 = RLF(38); const float r39 = RLF(39);
        const float r40 = RLF(40); const float r41 = RLF(41);
        const float r42 = RLF(42); const float r43 = RLF(43);
        const float r44 = RLF(44); const float r45 = RLF(45);
        const float r46 = RLF(46); const float r47 = RLF(47);
        const float r48 = RLF(48); const float r49 = RLF(49);
        __builtin_amdgcn_sched_barrier(0);   // fence: no fma hoisted into RL block

        const float rv = __builtin_amdgcn_rcpf(r0);  // off-chain vs dot
        A += __logf(r0);                             // off-chain
        const float pr = pcur * rv;                  // off-chain

        float c0 = 0.f, c1 = 0.f, c2 = 0.f, c3 = 0.f;
        float c4 = 0.f, c5 = 0.f, c6 = 0.f, c7 = 0.f;
        c0 = fmaf(r0,  et0.x,  c0);
        c1 = fmaf(r1,  et0.y,  c1);
        c2 = fmaf(r2,  et0.z,  c2);
        c3 = fmaf(r3,  et0.w,  c3);
        c4 = fmaf(r4,  et1.x,  c4);
        c5 = fmaf(r5,  et1.y,  c5);
        c6 = fmaf(r6,  et1.z,  c6);
        c7 = fmaf(r7,  et1.w,  c7);
        c0 = fmaf(r8,  et2.x,  c0);
        c1 = fmaf(r9,  et2.y,  c1);
        c2 = fmaf(r10, et2.z,  c2);
        c3 = fmaf(r11, et2.w,  c3);
        c4 = fmaf(r12, et3.x,  c4);
        c5 = fmaf(r13, et3.y,  c5);
        c6 = fmaf(r14, et3.z,  c6);
        c7 = fmaf(r15, et3.w,  c7);
        c0 = fmaf(r16, et4.x,  c0);
        c1 = fmaf(r17, et4.y,  c1);
        c2 = fmaf(r18, et4.z,  c2);
        c3 = fmaf(r19, et4.w,  c3);
        c4 = fmaf(r20, et5.x,  c4);
        c5 = fmaf(r21, et5.y,  c5);
        c6 = fmaf(r22, et5.z,  c6);
        c7 = fmaf(r23, et5.w,  c7);
        c0 = fmaf(r24, et6.x,  c0);
        c1 = fmaf(r25, et6.y,  c1);
        c2 = fmaf(r26, et6.z,  c2);
        c3 = fmaf(r27, et6.w,  c3);
        c4 = fmaf(r28, et7.x,  c4);
        c5 = fmaf(r29, et7.y,  c5);
        c6 = fmaf(r30, et7.z,  c6);
        c7 = fmaf(r31, et7.w,  c7);
        c0 = fmaf(r32, et8.x,  c0);
        c1 = fmaf(r33, et8.y,  c1);
        c2 = fmaf(r34, et8.z,  c2);
        c3 = fmaf(r35, et8.w,  c3);
        c4 = fmaf(r36, et9.x,  c4);
        c5 = fmaf(r37, et9.y,  c5);
        c6 = fmaf(r38, et9.z,  c6);
        c7 = fmaf(r39, et9.w,  c7);
        c0 = fmaf(r40, et10.x, c0);
        c1 = fmaf(r41, et10.y, c1);
        c2 = fmaf(r42, et10.z, c2);
        c3 = fmaf(r43, et10.w, c3);
        c4 = fmaf(r44, et11.x, c4);
        c5 = fmaf(r45, et11.y, c5);
        c6 = fmaf(r46, et11.z, c6);
        c7 = fmaf(r47, et11.w, c7);
        c0 = fmaf(r48, et12.x, c0);
        c1 = fmaf(r49, et12.y, c1);

        const float s = ((c0 + c1) + (c2 + c3)) + ((c4 + c5) + (c6 + c7));
        ue = s * pr;                                 // raw (un-normalized)

        pcur = pnext; q0 = q1; q1 = q2; q2 = q3; q3 = newem;
    }

    // den = A + log( sum_j v_j * exp(end_j) )   [alpha_j = A + log v_j]
    const float wv = (j < NLAB) ? (ue * __expf(endT[j])) : 0.f;
    const float den = A + __logf(wave_sum(wv));

    // numerator: gold path (contiguous mask -> parallel over t)
    const int* tg = labels + b * TLEN;
    float num = 0.f;
#pragma unroll
    for (int it = 0; it < 8; ++it) {
        const int t = lane + it * 64;
        if (t < len) {
            const int tag = tg[t];
            num += em[t * NLAB + tag];
            if (t >= 1) num += trans[tg[t - 1] * NLAB + tag];
        }
    }
    num = wave_sum(num);
    if (lane == 0) {
        num += startT[tg[0]] + endT[tg[len - 1]];
        // fused loss: out0 = -(mean llh); wprep zeroed out0[0]
        atomicAdd(out0, (den - num) * (1.0f / BATCH));
    }
}

extern "C" void kernel_launch(void* const* d_in, const int* in_sizes, int n_in,
                              void* d_out, int out_size, void* d_ws, size_t ws_size,
                              hipStream_t stream) {
    (void)in_sizes; (void)n_in; (void)out_size; (void)ws_size;
    const float* emb    = (const float*)d_in[0];
    const int*   labels = (const int*)d_in[1];
    const void*  mask   = d_in[2];
    const float* W      = (const float*)d_in[3];
    const float* bias   = (const float*)d_in[4];
    const float* startT = (const float*)d_in[5];
    const float* endT   = (const float*)d_in[6];
    const float* trans  = (const float*)d_in[7];

    float* out    = (float*)d_out;
    float* logits = out + 1;
    unsigned short* Bt = (unsigned short*)((char*)d_ws + 512);  // 96 KiB bf16 W^T

    wprep_kernel<<<(64 * DIM + 255) / 256, 256, 0, stream>>>(W, Bt, out);
    gemm_kernel<<<(BATCH * TLEN) / 128, 512, 0, stream>>>(emb, Bt, bias, logits);
    crf_kernel<<<BATCH, 64, 0, stream>>>(logits, labels, mask, startT, endT, trans, out);
}